// Round 1
// baseline (1033.572 us; speedup 1.0000x reference)
//
#include <hip/hip_runtime.h>
#include <hip/hip_bf16.h>

// ---- problem constants ----
#define B_    4
#define N_    8192
#define MD_   512
#define OC_   536        // HEADS*(FEAT+3)
#define HEADS_ 8
#define FEAT_ 64
#define NC_   32768      // 32^3 cells
#define ZTOT_ 67108864ll // B*HEADS*FEAT*NC
#define NKEYS_ 786432.0f // B*HEADS*3*N

// ============================================================
// Kernel 1: GEMM  kv[b][o][n] = sum_m W[o][m] * X[b][m][n]
// tile: 64 rows x 256 cols, BK=32, 256 threads, 8x8 per thread
// ============================================================
__global__ __launch_bounds__(256) void gemm_kernel(const float* __restrict__ W,
                                                   const float* __restrict__ X,
                                                   float* __restrict__ KV) {
  const int n0 = blockIdx.x * 256;
  const int m0 = blockIdx.y * 64;
  const int b  = blockIdx.z;
  __shared__ float Wt[32][68];    // Wt[k][m]
  __shared__ float In[32][260];   // In[k][n]
  const int t  = threadIdx.x;
  const int tx = t & 31;          // col group
  const int ty = t >> 5;          // row group (0..7)
  float acc[8][8];
#pragma unroll
  for (int r = 0; r < 8; ++r)
#pragma unroll
    for (int c = 0; c < 8; ++c) acc[r][c] = 0.f;

  const float* Xb = X + (size_t)b * MD_ * N_;
  for (int k0 = 0; k0 < MD_; k0 += 32) {
    // load W tile 64x32 (Wt[k][m])
#pragma unroll
    for (int i = 0; i < 8; ++i) {
      int idx = t + i * 256;
      int m = idx >> 5, k = idx & 31;
      int mm = m0 + m;
      Wt[k][m] = (mm < OC_) ? W[(size_t)mm * MD_ + (k0 + k)] : 0.f;
    }
    // load In tile 32x256 as float4
#pragma unroll
    for (int i = 0; i < 8; ++i) {
      int slot = t + i * 256;
      int k = slot >> 6, n4 = slot & 63;
      float4 v = *(const float4*)(Xb + (size_t)(k0 + k) * N_ + n0 + n4 * 4);
      *(float4*)&In[k][n4 * 4] = v;
    }
    __syncthreads();
#pragma unroll
    for (int k = 0; k < 32; ++k) {
      float a[8], bb[8];
      *(float4*)&a[0]  = *(const float4*)&Wt[k][ty * 8];
      *(float4*)&a[4]  = *(const float4*)&Wt[k][ty * 8 + 4];
      // two float4 cols: tx*4 and 128+tx*4 (16B/lane contiguous -> no bank conflict)
      *(float4*)&bb[0] = *(const float4*)&In[k][tx * 4];
      *(float4*)&bb[4] = *(const float4*)&In[k][128 + tx * 4];
#pragma unroll
      for (int r = 0; r < 8; ++r)
#pragma unroll
        for (int c = 0; c < 8; ++c)
          acc[r][c] = fmaf(a[r], bb[c], acc[r][c]);
    }
    __syncthreads();
  }
  // writeback
#pragma unroll
  for (int r = 0; r < 8; ++r) {
    int mm = m0 + ty * 8 + r;
    if (mm < OC_) {
      float* dst = KV + ((size_t)b * OC_ + mm) * N_ + n0;
      *(float4*)(dst + tx * 4)       = *(float4*)&acc[r][0];
      *(float4*)(dst + 128 + tx * 4) = *(float4*)&acc[r][4];
    }
  }
}

// ============================================================
// Kernel 2: BN stats per channel -> scale/shift
// scale[o] = gamma*rsqrt(var+eps); shift[o] = beta - mu*scale
// ============================================================
__global__ __launch_bounds__(256) void bn_kernel(const float* __restrict__ KV,
                                                 const float* __restrict__ kg,
                                                 const float* __restrict__ kb,
                                                 const float* __restrict__ vg,
                                                 const float* __restrict__ vb,
                                                 float* __restrict__ scale,
                                                 float* __restrict__ shift) {
  const int o = blockIdx.x;
  const int t = threadIdx.x;
  float s = 0.f, s2 = 0.f;
  for (int idx = t; idx < B_ * N_; idx += 256) {
    int bb = idx >> 13, n = idx & (N_ - 1);
    float v = KV[((size_t)bb * OC_ + o) * N_ + n];
    s += v; s2 += v * v;
  }
#pragma unroll
  for (int off = 32; off; off >>= 1) {
    s  += __shfl_down(s, off);
    s2 += __shfl_down(s2, off);
  }
  __shared__ float rs[4], rs2[4];
  if ((t & 63) == 0) { rs[t >> 6] = s; rs2[t >> 6] = s2; }
  __syncthreads();
  if (t == 0) {
    s  = rs[0] + rs[1] + rs[2] + rs[3];
    s2 = rs2[0] + rs2[1] + rs2[2] + rs2[3];
    const float inv = 1.0f / (B_ * N_);
    float mu  = s * inv;
    float var = s2 * inv - mu * mu;
    float g, be;
    if (o < 24) { g = kg[o]; be = kb[o]; }
    else        { g = vg[o - 24]; be = vb[o - 24]; }
    float sc = g * rsqrtf(var + 1e-5f);
    scale[o] = sc;
    shift[o] = be - mu * sc;
  }
}

// ============================================================
// Kernel 3: keys -> lattice -> splat (+ keys mean/var partials)
// one block = (b,h, 64 points); lane = feat during splat
// FINAL=false: Z layout (bh, cell, feat)  [coalesced atomics]
// FINAL=true : Z layout (bh, feat, cell)  [d_out direct fallback]
// ============================================================
template <bool FINAL>
__global__ __launch_bounds__(256) void splat_kernel(const float* __restrict__ KV,
                                                    const float* __restrict__ orig,
                                                    const float* __restrict__ proj,
                                                    const float* __restrict__ scale,
                                                    const float* __restrict__ shift,
                                                    float* __restrict__ Z,
                                                    float* __restrict__ kacc) {
  const int bh = blockIdx.x >> 7;
  const int n0 = (blockIdx.x & 127) << 6;
  const int b = bh >> 3, h = bh & 7;
  __shared__ float vals[64][65];
  __shared__ int   cellS[64];
  __shared__ float rS[64][4];
  const int t = threadIdx.x;
  const float* KVb = KV + (size_t)b * OC_ * N_;
  const int ch0 = 24 + h * 64;

  // stage BN'd values tile (64 feat x 64 points)
#pragma unroll
  for (int i = 0; i < 16; ++i) {
    int idx = t + i * 256;
    int f = idx >> 6, p = idx & 63;
    int ch = ch0 + f;
    float v = KVb[(size_t)ch * N_ + n0 + p];
    vals[f][p] = fmaf(v, scale[ch], shift[ch]);
  }

  // per-point lattice coords (threads 0..63 = wave 0)
  if (t < 64) {
    const int n = n0 + t;
    float pt[3];
#pragma unroll
    for (int k = 0; k < 3; ++k) {
      int ch = h * 3 + k;
      float kr = fmaf(KVb[(size_t)ch * N_ + n], scale[ch], shift[ch]);
      pt[k] = orig[((size_t)b * 3 + k) * N_ + n] + kr;
    }
    float ksum = 0.f, ksq = 0.f;
    int cell = 0;
    float rr[3];
#pragma unroll
    for (int d = 0; d < 3; ++d) {
      const float* pr = proj + (h * 3 + d) * 3;
      float key = pr[0] * pt[0] + pr[1] * pt[1] + pr[2] * pt[2];
      ksum += key; ksq += key * key;
      float lat = tanhf(key);
      float c = (lat + 1.0f) * 15.5f;
      float fl = floorf(c);
      fl = fminf(fmaxf(fl, 0.0f), 30.0f);
      rr[d] = c - fl;
      cell += (int)fl * ((d == 0) ? 1024 : (d == 1) ? 32 : 1);
    }
    cellS[t] = cell;
    rS[t][0] = rr[0]; rS[t][1] = rr[1]; rS[t][2] = rr[2];
#pragma unroll
    for (int off = 32; off; off >>= 1) {
      ksum += __shfl_down(ksum, off);
      ksq  += __shfl_down(ksq, off);
    }
    if (t == 0) { atomicAdd(&kacc[0], ksum); atomicAdd(&kacc[1], ksq); }
  }
  __syncthreads();

  // splat: wave w takes 16 points, lane = feat
  const int w = t >> 6, l = t & 63;
  for (int pi = 0; pi < 16; ++pi) {
    int p = w * 16 + pi;
    int cell = cellS[p];
    float r0 = rS[p][0], r1 = rS[p][1], r2 = rS[p][2];
    float u0 = 1.f - r0, u1 = 1.f - r1, u2 = 1.f - r2;
    float v = vals[l][p];
#pragma unroll
    for (int c = 0; c < 8; ++c) {
      float wt = ((c & 4) ? r0 : u0) * ((c & 2) ? r1 : u1) * ((c & 1) ? r2 : u2);
      int cc = cell + ((c & 4) ? 1024 : 0) + ((c & 2) ? 32 : 0) + (c & 1);
      if (FINAL)
        atomicAdd(Z + (size_t)(bh * 64 + l) * NC_ + cc, v * wt);
      else
        atomicAdd(Z + ((size_t)bh * NC_ + cc) * 64 + l, v * wt);
    }
  }
}

// ============================================================
// Kernel 4: transpose (bh,cell,feat) -> (bh,feat,cell) + occ count
// ============================================================
__global__ __launch_bounds__(256) void transpose_kernel(const float* __restrict__ ztmp,
                                                        float* __restrict__ zout,
                                                        unsigned int* __restrict__ occ) {
  const int slab = blockIdx.x >> 9;          // bh
  const int c0   = (blockIdx.x & 511) << 6;  // cell tile base
  const float* src = ztmp + ((size_t)slab * NC_ + c0) * 64;
  __shared__ float T[64][65];
  const int t = threadIdx.x;
  unsigned int cnt = 0;
#pragma unroll
  for (int i = 0; i < 16; ++i) {
    int idx = t + i * 256;
    int cell = idx >> 6, f = idx & 63;
    float v = src[(size_t)cell * 64 + f];
    cnt += (fabsf(v) > 1e-9f) ? 1u : 0u;
    T[f][cell] = v;
  }
  __syncthreads();
  float* dst = zout + (size_t)slab * 64 * NC_ + c0;
#pragma unroll
  for (int i = 0; i < 16; ++i) {
    int idx = t + i * 256;
    int f = idx >> 6, cell = idx & 63;
    dst[(size_t)f * NC_ + cell] = T[f][cell];
  }
#pragma unroll
  for (int off = 32; off; off >>= 1) cnt += __shfl_down(cnt, off);
  __shared__ unsigned int wc[4];
  if ((t & 63) == 0) wc[t >> 6] = cnt;
  __syncthreads();
  if (t == 0) atomicAdd(occ, wc[0] + wc[1] + wc[2] + wc[3]);
}

// occ count over final-layout z (fallback path)
__global__ __launch_bounds__(256) void count_kernel(const float* __restrict__ Z,
                                                    unsigned int* __restrict__ occ) {
  unsigned int cnt = 0;
  for (long long i = (long long)blockIdx.x * blockDim.x + threadIdx.x; i < ZTOT_;
       i += (long long)gridDim.x * blockDim.x)
    cnt += (fabsf(Z[i]) > 1e-9f) ? 1u : 0u;
#pragma unroll
  for (int off = 32; off; off >>= 1) cnt += __shfl_down(cnt, off);
  __shared__ unsigned int wc[4];
  const int t = threadIdx.x;
  if ((t & 63) == 0) wc[t >> 6] = cnt;
  __syncthreads();
  if (t == 0) atomicAdd(occ, wc[0] + wc[1] + wc[2] + wc[3]);
}

__global__ void finalize_kernel(const unsigned int* __restrict__ occ,
                                const float* __restrict__ kacc,
                                float* __restrict__ tail) {
  float mean = kacc[0] / NKEYS_;
  tail[0] = (float)(*occ) * (1.0f / 2048.0f);
  tail[1] = mean;
  tail[2] = kacc[1] / NKEYS_ - mean * mean;
}

// ============================================================
extern "C" void kernel_launch(void* const* d_in, const int* in_sizes, int n_in,
                              void* d_out, int out_size, void* d_ws, size_t ws_size,
                              hipStream_t stream) {
  const float* X    = (const float*)d_in[0];
  const float* orig = (const float*)d_in[1];
  const float* W    = (const float*)d_in[2];
  const float* kg   = (const float*)d_in[3];
  const float* kb   = (const float*)d_in[4];
  const float* vg   = (const float*)d_in[5];
  const float* vb   = (const float*)d_in[6];
  const float* proj = (const float*)d_in[7];
  float* out = (float*)d_out;

  // ws layout: stats block (8 KiB) then big scratch
  float* stats = (float*)d_ws;
  float* scale = stats;                    // [536]
  float* shift = stats + 536;              // [536]
  float* kacc  = stats + 1072;             // [2]
  unsigned int* occ = (unsigned int*)(stats + 1074);
  char* big = (char*)d_ws + 8192;

  const size_t ztmp_bytes = (size_t)ZTOT_ * 4;   // 256 MiB
  const bool planA = ws_size >= ztmp_bytes + 8192;

  hipMemsetAsync(kacc, 0, 12, stream);  // kacc[0..1] + occ

  if (planA) {
    float* kv   = out;                   // z region reused as kv scratch
    float* ztmp = (float*)big;
    hipMemsetAsync(ztmp, 0, ztmp_bytes, stream);
    gemm_kernel<<<dim3(N_ / 256, 9, B_), 256, 0, stream>>>(W, X, kv);
    bn_kernel<<<OC_, 256, 0, stream>>>(kv, kg, kb, vg, vb, scale, shift);
    splat_kernel<false><<<B_ * HEADS_ * (N_ / 64), 256, 0, stream>>>(
        kv, orig, proj, scale, shift, ztmp, kacc);
    transpose_kernel<<<32 * 512, 256, 0, stream>>>(ztmp, out, occ);
    finalize_kernel<<<1, 1, 0, stream>>>(occ, kacc, out + ZTOT_);
  } else {
    // fallback: kv in ws, splat straight into d_out final layout
    float* kv = (float*)big;
    hipMemsetAsync(out, 0, ztmp_bytes, stream);
    gemm_kernel<<<dim3(N_ / 256, 9, B_), 256, 0, stream>>>(W, X, kv);
    bn_kernel<<<OC_, 256, 0, stream>>>(kv, kg, kb, vg, vb, scale, shift);
    splat_kernel<true><<<B_ * HEADS_ * (N_ / 64), 256, 0, stream>>>(
        kv, orig, proj, scale, shift, out, kacc);
    count_kernel<<<2048, 256, 0, stream>>>(out, occ);
    finalize_kernel<<<1, 1, 0, stream>>>(occ, kacc, out + ZTOT_);
  }
}